// Round 11
// baseline (77.764 us; speedup 1.0000x reference)
//
#include <hip/hip_runtime.h>

#define BB 4
#define NN 512
#define NH 256
#define DD 64

typedef __attribute__((ext_vector_type(8))) short bf16x8;
typedef __attribute__((ext_vector_type(16))) float f32x16;
union BF8 { bf16x8 v; unsigned int u[4]; };

__device__ __forceinline__ float wred_sum(float v) {
  v += __shfl_xor(v, 32);
  v += __shfl_xor(v, 16);
  v += __shfl_xor(v, 8);
  v += __shfl_xor(v, 4);
  v += __shfl_xor(v, 2);
  v += __shfl_xor(v, 1);
  return v;
}

__device__ __forceinline__ float wred_max(float v) {
  v = fmaxf(v, __shfl_xor(v, 32));
  v = fmaxf(v, __shfl_xor(v, 16));
  v = fmaxf(v, __shfl_xor(v, 8));
  v = fmaxf(v, __shfl_xor(v, 4));
  v = fmaxf(v, __shfl_xor(v, 2));
  v = fmaxf(v, __shfl_xor(v, 1));
  return v;
}

__device__ __forceinline__ unsigned int cvtpk_bf16(float lo, float hi) {
  unsigned int r;
  asm("v_cvt_pk_bf16_f32 %0, %1, %2" : "=v"(r) : "v"(lo), "v"(hi));
  return r;
}

__device__ __forceinline__ float fast_exp2(float x) {
  float r;
  asm("v_exp_f32 %0, %1" : "=v"(r) : "v"(x));
  return r;
}

__device__ __forceinline__ float fast_tanh(float t) {
  t = fminf(15.f, fmaxf(-15.f, t));
  float z = __expf(2.f * t);
  return 1.f - 2.f * __builtin_amdgcn_rcpf(z + 1.f);
}

__device__ __forceinline__ float bflo(unsigned int u) { return __uint_as_float(u << 16); }
__device__ __forceinline__ float bfhi(unsigned int u) { return __uint_as_float(u & 0xffff0000u); }

// swizzled byte address within the bf16 X tile: row-major [512][64]bf16 (128 B rows)
__device__ __forceinline__ unsigned int xswz(int row, int byte_in_row) {
  return (unsigned int)((row * 128 + byte_in_row) ^ ((row & 7) << 4));
}

// K1: x[b,n,:] = (n<256 ? x1@W_t1+b_t1 : x2@W_t2+b_t2)
__global__ __launch_bounds__(256)
void k1_build_x(const float* __restrict__ x1, const float* __restrict__ x2,
                const float* __restrict__ W_t1, const float* __restrict__ b_t1,
                const float* __restrict__ W_t2, const float* __restrict__ b_t2,
                float* __restrict__ X) {
  const int tid = threadIdx.x;
  const int lane = tid & 63;
  const int rq = tid >> 6;
  const int r = blockIdx.x * 4 + rq;
  const int b = r >> 9;
  const int n = r & 511;
  const float* src; const float* W; const float* bias;
  if (n < NH) { src = x1 + (b * NH + n) * DD;        W = W_t1; bias = b_t1; }
  else        { src = x2 + (b * NH + (n - NH)) * DD; W = W_t2; bias = b_t2; }
  const float4* s4 = reinterpret_cast<const float4*>(src);
  float t0 = 0.f, t1 = 0.f, t2 = 0.f, t3 = 0.f;
#pragma unroll
  for (int c = 0; c < 16; ++c) {
    const float4 v = s4[c];
    t0 = fmaf(v.x, W[(4 * c + 0) * DD + lane], t0);
    t1 = fmaf(v.y, W[(4 * c + 1) * DD + lane], t1);
    t2 = fmaf(v.z, W[(4 * c + 2) * DD + lane], t2);
    t3 = fmaf(v.w, W[(4 * c + 3) * DD + lane], t3);
  }
  X[r * DD + lane] = ((t0 + t1) + (t2 + t3)) + bias[lane];
}

// K3: fused scores(MFMA) + master-mean + softmax + agg + y(selu) + logits.
// 512 thr = 8 waves, 4 rows/block, grid (128,4) = 512 blocks -> 2 blocks/CU
// (LDS ~78 KB, VGPR capped 128 via (512,4)). x_j in REGISTERS (no per-lane-row
// LDS reads -> no bank conflicts, R9's mistake); x_i/agg reads are row-broadcast.
__global__ __launch_bounds__(512, 4)
void k3_fused(const float* __restrict__ X,
              const float* __restrict__ W_att, const float* __restrict__ b_att,
              const float* __restrict__ w11, const float* __restrict__ w22,
              const float* __restrict__ w12,
              const float* __restrict__ W_attM, const float* __restrict__ b_attM,
              const float* __restrict__ wM,
              const float* __restrict__ W_pa, const float* __restrict__ b_pa,
              const float* __restrict__ W_po, const float* __restrict__ b_po,
              const float* __restrict__ gamma, const float* __restrict__ beta,
              float* __restrict__ master, float* __restrict__ logits,
              float* __restrict__ out) {
  const int b = blockIdx.y;
  const int i0 = blockIdx.x * 4;
  const int tid = threadIdx.x;
  const int lane = tid & 63;
  const int w = tid >> 6;          // 0..7
  const int l31 = lane & 31;
  const int half = lane >> 5;
  const int j0 = w << 6;           // 64-wide j chunk

  __shared__ __align__(16) unsigned int Xbf[NN * 32];  // 64 KB bf16-pair tile, swizzled
  __shared__ __align__(16) float sc[4 * NN];           // 8 KB
  __shared__ __align__(16) float red2[16][DD];         // 4 KB
  __shared__ __align__(16) float aggL[4][DD];          // 1 KB
  __shared__ __align__(16) float tblB[64];             // K2E*b_att, C-reg order
  __shared__ __align__(16) float tblW[2][64];          // -2*wsel, C-reg order
  __shared__ __align__(16) float mastL[64];
  __shared__ __align__(16) float smax[8];
  __shared__ __align__(16) float ssum8[8];

  const float* __restrict__ Xb = X + b * NN * DD;
  const float K2E = 2.8853900817779268f;  // 2*log2(e)
  const int itype = (i0 >= NH);
  const int jtype = (w >= 4);

  // ---- stage X[b] -> bf16 swizzled tile; thread t handles row t (R9-proven) ----
  {
    const int r = tid;
    const float4* src = reinterpret_cast<const float4*>(&Xb[r * DD]);
#pragma unroll
    for (int s = 0; s < 8; ++s) {          // slot s = 16 B = 8 bf16 = d [8s, 8s+8)
      const float4 a = src[s * 2];
      const float4 c = src[s * 2 + 1];
      uint4 v;
      v.x = cvtpk_bf16(a.x, a.y);
      v.y = cvtpk_bf16(a.z, a.w);
      v.z = cvtpk_bf16(c.x, c.y);
      v.w = cvtpk_bf16(c.z, c.w);
      *reinterpret_cast<uint4*>(reinterpret_cast<char*>(Xbf) + xswz(r, s * 16)) = v;
    }
  }
  // coefficient tables (R9-proven), idx = ot*32 + hf*16 + r
  if (tid < 64) {
    const int ot = tid >> 5, hf = (tid >> 4) & 1, r = tid & 15;
    const int o = ot * 32 + (r & 3) + 8 * (r >> 2) + 4 * hf;
    tblB[tid] = K2E * b_att[o];
  } else if (tid >= 128 && tid < 256) {
    const int t = tid - 128;
    const int jt = t >> 6;
    const int idx = t & 63;
    const int ot = idx >> 5, hf = (idx >> 4) & 1, r = idx & 15;
    const int o = ot * 32 + (r & 3) + 8 * (r >> 2) + 4 * hf;
    const float* wsl = itype ? (jt ? w22 : w12) : (jt ? w12 : w11);
    tblW[jt][idx] = -2.f * wsl[o];
  }

  // ---- i-invariant registers: W^T fragments (32 VGPR, R3-proven) ----
  BF8 Wp[2][4];
#pragma unroll
  for (int ot = 0; ot < 2; ++ot)
#pragma unroll
    for (int kt = 0; kt < 4; ++kt) {
      const int o = ot * 32 + l31;
#pragma unroll
      for (int p = 0; p < 4; ++p) {
        const int d0 = kt * 16 + half * 8 + 2 * p;
        Wp[ot][kt].u[p] = cvtpk_bf16(W_att[d0 * DD + o], W_att[(d0 + 1) * DD + o]);
      }
    }

  // x_j packed bf16 in regs (32 VGPR, R7-proven): col j = j0 + jt*32 + l31
  BF8 Xf[2][4];
#pragma unroll
  for (int jt = 0; jt < 2; ++jt)
#pragma unroll
    for (int kt = 0; kt < 4; ++kt) {
      const float* base = Xb + (j0 + jt * 32 + l31) * DD + kt * 16 + half * 8;
      const float4 a = *reinterpret_cast<const float4*>(base);
      const float4 c = *reinterpret_cast<const float4*>(base + 4);
      Xf[jt][kt].u[0] = cvtpk_bf16(a.x, a.y);
      Xf[jt][kt].u[1] = cvtpk_bf16(a.z, a.w);
      Xf[jt][kt].u[2] = cvtpk_bf16(c.x, c.y);
      Xf[jt][kt].u[3] = cvtpk_bf16(c.z, c.w);
    }

  const float* wsel = itype ? (jtype ? w22 : w12) : (jtype ? w12 : w11);
  const float swv = wred_sum(wsel[lane]);   // sum_o wsel[o], wave-uniform

  __syncthreads();   // bar1: Xbf + tables ready

  // ---- master mean from bf16 tile (R9-proven): lane <-> d-pair ----
  {
    float se = 0.f, so = 0.f;
    const int r0 = w * 32 + half * 256;     // 8 waves x 2 halves x 32 rows = 512
    for (int r = r0; r < r0 + 32; ++r) {
      const unsigned int u = *reinterpret_cast<const unsigned int*>(
          reinterpret_cast<const char*>(Xbf) + xswz(r, l31 * 4));
      se += bflo(u); so += bfhi(u);
    }
    float2 pr; pr.x = se; pr.y = so;
    *reinterpret_cast<float2*>(&red2[w * 2 + half][l31 * 2]) = pr;
  }
  __syncthreads();   // bar2
  if (w == 0) {
    float s = 0.f;
#pragma unroll
    for (int k = 0; k < 16; ++k) s += red2[k][lane];
    s *= (1.f / 512.f);
    mastL[lane] = s;
    if (blockIdx.x == 0) master[b * DD + lane] = s;
  }

  // ---- phase 1: scores for 4 rows; x_i broadcast from tile, x_j from regs ----
#pragma unroll 1
  for (int ii = 0; ii < 4; ++ii) {
    const int irow = i0 + ii;
#pragma unroll
    for (int jt = 0; jt < 2; ++jt) {
      f32x16 C0 = {}, C1 = {};
#pragma unroll
      for (int kt = 0; kt < 4; ++kt) {
        // x_i fragment: broadcast b128 (2 addresses by half) - conflict-free
        const uint4 xiu = *reinterpret_cast<const uint4*>(
            reinterpret_cast<const char*>(Xbf) + xswz(irow, (2 * kt + half) * 16));
        const BF8 xj = Xf[jt][kt];
        BF8 Bi;
        Bi.u[0] = cvtpk_bf16(bflo(xiu.x) * bflo(xj.u[0]), bfhi(xiu.x) * bfhi(xj.u[0]));
        Bi.u[1] = cvtpk_bf16(bflo(xiu.y) * bflo(xj.u[1]), bfhi(xiu.y) * bfhi(xj.u[1]));
        Bi.u[2] = cvtpk_bf16(bflo(xiu.z) * bflo(xj.u[2]), bfhi(xiu.z) * bfhi(xj.u[2]));
        Bi.u[3] = cvtpk_bf16(bflo(xiu.w) * bflo(xj.u[3]), bfhi(xiu.w) * bfhi(xj.u[3]));
        C0 = __builtin_amdgcn_mfma_f32_32x32x16_bf16(Wp[0][kt].v, Bi.v, C0, 0, 0, 0);
        C1 = __builtin_amdgcn_mfma_f32_32x32x16_bf16(Wp[1][kt].v, Bi.v, C1, 0, 0, 0);
      }
      // epilogue (R9-proven exp form): arg = K2E*C + tblB; p += tblW * rcp(2^arg + 1)
      float p = 0.f;
      const int base = half * 16;
#pragma unroll
      for (int r = 0; r < 16; ++r) {
        const float a0 = fmaf(C0[r], K2E, tblB[base + r]);
        const float e0 = fast_exp2(a0);
        p = fmaf(tblW[jtype][base + r], __builtin_amdgcn_rcpf(e0 + 1.f), p);
        const float a1 = fmaf(C1[r], K2E, tblB[32 + base + r]);
        const float e1 = fast_exp2(a1);
        p = fmaf(tblW[jtype][32 + base + r], __builtin_amdgcn_rcpf(e1 + 1.f), p);
      }
      p += __shfl_xor(p, 32);   // combine o-halves
      if (lane < 32) sc[ii * NN + j0 + jt * 32 + l31] = swv + p;
    }
  }
  __syncthreads();   // bar3: scores + mastL ready

  // ---- phase 2 (R9-proven): row = w&3, part = w>>2 ----
  const int row = w & 3, part = w >> 2;
  const int irow = i0 + row;
  float v[4];
#pragma unroll
  for (int k = 0; k < 4; ++k) v[k] = sc[row * NN + part * 256 + 64 * k + lane];
  float mx = fmaxf(fmaxf(v[0], v[1]), fmaxf(v[2], v[3]));
  mx = wred_max(mx);
  if (lane == 0) smax[w] = mx;
  __syncthreads();   // bar4
  mx = fmaxf(smax[w], smax[w ^ 4]);
  float es = 0.f;
#pragma unroll
  for (int k = 0; k < 4; ++k) { v[k] = __expf(v[k] - mx); es += v[k]; }
  es = wred_sum(es);
  if (lane == 0) ssum8[w] = es;
  __syncthreads();   // bar5
  const float inv = __builtin_amdgcn_rcpf(ssum8[w] + ssum8[w ^ 4]);
#pragma unroll
  for (int k = 0; k < 4; ++k) sc[row * NN + part * 256 + 64 * k + lane] = v[k] * inv;

  // agg: lane <-> d-pair; lane-half <-> j-subrange of 128 (row-broadcast, 2/bank)
  {
    float ae = 0.f, ao = 0.f;
    const int jb = part * 256 + half * 128;
    for (int jj = 0; jj < 128; ++jj) {
      const int j = jb + jj;
      const float at = sc[row * NN + j];
      const unsigned int u = *reinterpret_cast<const unsigned int*>(
          reinterpret_cast<const char*>(Xbf) + xswz(j, l31 * 4));
      ae = fmaf(at, bflo(u), ae);
      ao = fmaf(at, bfhi(u), ao);
    }
    float2 pr; pr.x = ae; pr.y = ao;
    *reinterpret_cast<float2*>(&red2[8 * part + 2 * row + half][l31 * 2]) = pr;
  }
  __syncthreads();   // bar6

  // x[irow] into regs (8 broadcast b128 reads), unpacked on use
  uint4 xr[8];
#pragma unroll
  for (int s = 0; s < 8; ++s)
    xr[s] = *reinterpret_cast<const uint4*>(
        reinterpret_cast<const char*>(Xbf) + xswz(irow, s * 16));

  if (part == 0) {
    // y = selu(BN(agg@W_pa + x@W_po + biases))
    const float aggv = red2[2 * row][lane] + red2[2 * row + 1][lane] +
                       red2[8 + 2 * row][lane] + red2[8 + 2 * row + 1][lane];
    aggL[row][lane] = aggv;
    float y = b_pa[lane] + b_po[lane];
#pragma unroll
    for (int s = 0; s < 8; ++s) {
      const float xd[8] = {bflo(xr[s].x), bfhi(xr[s].x), bflo(xr[s].y), bfhi(xr[s].y),
                           bflo(xr[s].z), bfhi(xr[s].z), bflo(xr[s].w), bfhi(xr[s].w)};
#pragma unroll
      for (int q = 0; q < 8; ++q) {
        const int d = s * 8 + q;
        y = fmaf(aggL[row][d], W_pa[d * DD + lane], y);
        y = fmaf(xd[q], W_po[d * DD + lane], y);
      }
    }
    const float RSQ = 0.9999950000374997f;   // 1/sqrt(1+1e-5)
    y = y * RSQ * gamma[lane] + beta[lane];
    const float SC_ = 1.0507009873554805f;
    const float AL = 1.6732632423543772f;
    y = (y > 0.f) ? (SC_ * y) : (SC_ * AL * (__expf(y) - 1.f));
    const int off = (irow < NH) ? ((b * NH + irow) * DD + lane)
                                : (BB * NH * DD + (b * NH + (irow - NH)) * DD + lane);
    out[off] = y;
  } else {
    // logits[b,irow] = wM . tanh((x_i*master)@W_attM + b_attM)
    float lg = b_attM[lane];
#pragma unroll
    for (int s = 0; s < 8; ++s) {
      const float xd[8] = {bflo(xr[s].x), bfhi(xr[s].x), bflo(xr[s].y), bfhi(xr[s].y),
                           bflo(xr[s].z), bfhi(xr[s].z), bflo(xr[s].w), bfhi(xr[s].w)};
#pragma unroll
      for (int q = 0; q < 8; ++q) {
        const int d = s * 8 + q;
        lg = fmaf(xd[q] * mastL[d], W_attM[d * DD + lane], lg);
      }
    }
    const float th = fast_tanh(lg);
    const float s = wred_sum(th * wM[lane]);
    if (lane == 0) logits[b * NN + irow] = s;
  }
}

// K4: softmax_n(logits) -> agg_m -> master_new (tail of out)
__global__ __launch_bounds__(256)
void k4_master_new(const float* __restrict__ X, const float* __restrict__ master,
                   const float* __restrict__ logits,
                   const float* __restrict__ W_paM, const float* __restrict__ b_paM,
                   const float* __restrict__ W_poM, const float* __restrict__ b_poM,
                   float* __restrict__ out) {
  const int b = blockIdx.x;
  const int tid = threadIdx.x;
  const int lane = tid & 63;
  const int q = tid >> 6;
  __shared__ float red[4][DD];
  __shared__ float r4[4];
  __shared__ float aggm_s[DD];
  __shared__ float mrow_s[DD];
  const float* lg = logits + b * NN;
  const float v0 = lg[tid];
  const float v1 = lg[tid + 256];
  float mx = wred_max(fmaxf(v0, v1));
  if (lane == 0) r4[q] = mx;
  __syncthreads();
  mx = fmaxf(fmaxf(r4[0], r4[1]), fmaxf(r4[2], r4[3]));
  float es = __expf(v0 - mx) + __expf(v1 - mx);
  es = wred_sum(es);
  __syncthreads();
  if (lane == 0) r4[q] = es;
  __syncthreads();
  const float S = r4[0] + r4[1] + r4[2] + r4[3];
  const float invS = 1.f / S;

  float acc = 0.f;
  for (int nn = q * 128; nn < q * 128 + 128; ++nn) {
    const float a = __expf(lg[nn] - mx);
    acc = fmaf(a, X[(b * NN + nn) * DD + lane], acc);
  }
  red[q][lane] = acc;
  __syncthreads();
  if (q == 0) {
    aggm_s[lane] =
        (red[0][lane] + red[1][lane] + red[2][lane] + red[3][lane]) * invS;
    mrow_s[lane] = master[b * DD + lane];
  }
  __syncthreads();
  float p = 0.f;
  for (int d = q * 16; d < q * 16 + 16; ++d) {
    p = fmaf(aggm_s[d], W_paM[d * DD + lane], p);
    p = fmaf(mrow_s[d], W_poM[d * DD + lane], p);
  }
  __syncthreads();
  red[q][lane] = p;
  __syncthreads();
  if (q == 0) {
    out[2 * BB * NH * DD + b * DD + lane] =
        red[0][lane] + red[1][lane] + red[2][lane] + red[3][lane] +
        b_paM[lane] + b_poM[lane];
  }
}

extern "C" void kernel_launch(void* const* d_in, const int* in_sizes, int n_in,
                              void* d_out, int out_size, void* d_ws, size_t ws_size,
                              hipStream_t stream) {
  const float* x1    = (const float*)d_in[0];
  const float* x2    = (const float*)d_in[1];
  const float* W_t1  = (const float*)d_in[2];
  const float* b_t1  = (const float*)d_in[3];
  const float* W_t2  = (const float*)d_in[4];
  const float* b_t2  = (const float*)d_in[5];
  const float* W_att = (const float*)d_in[6];
  const float* b_att = (const float*)d_in[7];
  const float* W_attM = (const float*)d_in[8];
  const float* b_attM = (const float*)d_in[9];
  const float* w11   = (const float*)d_in[10];
  const float* w22   = (const float*)d_in[11];
  const float* w12   = (const float*)d_in[12];
  const float* wM    = (const float*)d_in[13];
  const float* W_pa  = (const float*)d_in[14];
  const float* b_pa  = (const float*)d_in[15];
  const float* W_po  = (const float*)d_in[16];
  const float* b_po  = (const float*)d_in[17];
  const float* W_paM = (const float*)d_in[18];
  const float* b_paM = (const float*)d_in[19];
  const float* W_poM = (const float*)d_in[20];
  const float* b_poM = (const float*)d_in[21];
  const float* gamma = (const float*)d_in[22];
  const float* beta  = (const float*)d_in[23];

  float* ws     = (float*)d_ws;
  float* X      = ws;            // 131072 floats
  float* master = ws + 131072;   // 256
  float* logits = ws + 131328;   // 2048
  float* out    = (float*)d_out;

  k1_build_x<<<512, 256, 0, stream>>>(x1, x2, W_t1, b_t1, W_t2, b_t2, X);
  k3_fused<<<dim3(128, 4), 512, 0, stream>>>(X, W_att, b_att, w11, w22, w12,
                                             W_attM, b_attM, wM, W_pa, b_pa,
                                             W_po, b_po, gamma, beta,
                                             master, logits, out);
  k4_master_new<<<4, 256, 0, stream>>>(X, master, logits, W_paM, b_paM, W_poM, b_poM, out);
}

// Round 12
// 56.406 us; speedup vs baseline: 1.3786x; 1.3786x over previous
//
#include <hip/hip_runtime.h>

#define BB 4
#define NN 512
#define NH 256
#define DD 64

typedef __attribute__((ext_vector_type(8))) short bf16x8;
typedef __attribute__((ext_vector_type(16))) float f32x16;
union BF8 { bf16x8 v; unsigned int u[4]; };

__device__ __forceinline__ float wred_sum(float v) {
  v += __shfl_xor(v, 32);
  v += __shfl_xor(v, 16);
  v += __shfl_xor(v, 8);
  v += __shfl_xor(v, 4);
  v += __shfl_xor(v, 2);
  v += __shfl_xor(v, 1);
  return v;
}

__device__ __forceinline__ float wred_max(float v) {
  v = fmaxf(v, __shfl_xor(v, 32));
  v = fmaxf(v, __shfl_xor(v, 16));
  v = fmaxf(v, __shfl_xor(v, 8));
  v = fmaxf(v, __shfl_xor(v, 4));
  v = fmaxf(v, __shfl_xor(v, 2));
  v = fmaxf(v, __shfl_xor(v, 1));
  return v;
}

__device__ __forceinline__ unsigned int cvtpk_bf16(float lo, float hi) {
  unsigned int r;
  asm("v_cvt_pk_bf16_f32 %0, %1, %2" : "=v"(r) : "v"(lo), "v"(hi));
  return r;
}

__device__ __forceinline__ float fast_exp2(float x) {
  float r;
  asm("v_exp_f32 %0, %1" : "=v"(r) : "v"(x));
  return r;
}

__device__ __forceinline__ float fast_tanh(float t) {
  t = fminf(15.f, fmaxf(-15.f, t));
  float z = __expf(2.f * t);
  return 1.f - 2.f * __builtin_amdgcn_rcpf(z + 1.f);
}

__device__ __forceinline__ float bflo(unsigned int u) { return __uint_as_float(u << 16); }
__device__ __forceinline__ float bfhi(unsigned int u) { return __uint_as_float(u & 0xffff0000u); }

// K1: x[b,n,:] = (n<256 ? x1@W_t1+b_t1 : x2@W_t2+b_t2)
__global__ __launch_bounds__(256)
void k1_build_x(const float* __restrict__ x1, const float* __restrict__ x2,
                const float* __restrict__ W_t1, const float* __restrict__ b_t1,
                const float* __restrict__ W_t2, const float* __restrict__ b_t2,
                float* __restrict__ X) {
  const int tid = threadIdx.x;
  const int lane = tid & 63;
  const int rq = tid >> 6;
  const int r = blockIdx.x * 4 + rq;
  const int b = r >> 9;
  const int n = r & 511;
  const float* src; const float* W; const float* bias;
  if (n < NH) { src = x1 + (b * NH + n) * DD;        W = W_t1; bias = b_t1; }
  else        { src = x2 + (b * NH + (n - NH)) * DD; W = W_t2; bias = b_t2; }
  const float4* s4 = reinterpret_cast<const float4*>(src);
  float t0 = 0.f, t1 = 0.f, t2 = 0.f, t3 = 0.f;
#pragma unroll
  for (int c = 0; c < 16; ++c) {
    const float4 v = s4[c];
    t0 = fmaf(v.x, W[(4 * c + 0) * DD + lane], t0);
    t1 = fmaf(v.y, W[(4 * c + 1) * DD + lane], t1);
    t2 = fmaf(v.z, W[(4 * c + 2) * DD + lane], t2);
    t3 = fmaf(v.w, W[(4 * c + 3) * DD + lane], t3);
  }
  X[r * DD + lane] = ((t0 + t1) + (t2 + t3)) + bias[lane];
}

// K_SC: symmetric-triangle scores -> scG (both mirror locations written).
// 512 thr = 8 waves; grid (128,4) = 512 blocks -> 2 blocks/CU; tiny LDS.
// Block bx handles 2-row strips k=bx (rows 2bx..2bx+1) and k'=255-bx,
// each over j-chunks >= the strip's diagonal chunk: uniform 34 jobs/block.
// Job = 1 row x 32 j. Write ownership: only j >= row (direct + transpose).
__global__ __launch_bounds__(512, 1)
void k_sc(const float* __restrict__ X,
          const float* __restrict__ W_att, const float* __restrict__ b_att,
          const float* __restrict__ w11, const float* __restrict__ w22,
          const float* __restrict__ w12,
          float* __restrict__ scG) {
  const int b = blockIdx.y;
  const int bx = blockIdx.x;           // 0..127
  const int tid = threadIdx.x;
  const int lane = tid & 63;
  const int w = tid >> 6;              // 0..7
  const int l31 = lane & 31;
  const int half = lane >> 5;

  __shared__ __align__(16) float tblB[64];      // K2E*b_att, C-reg order
  __shared__ __align__(16) float tblW[4][64];   // -2*wsel per (it*2+jt)
  __shared__ __align__(16) float swv4[4];       // sum_o wsel per comb

  const float* __restrict__ Xb = X + b * NN * DD;
  float* __restrict__ scb = scG + b * NN * NN;
  const float K2E = 2.8853900817779268f;

  if (tid < 64) {
    const int ot = tid >> 5, hf = (tid >> 4) & 1, r = tid & 15;
    const int o = ot * 32 + (r & 3) + 8 * (r >> 2) + 4 * hf;
    tblB[tid] = K2E * b_att[o];
  }
  if (tid >= 64 && tid < 320) {
    const int t = tid - 64;            // 0..255
    const int comb = t >> 6;           // it*2+jt
    const int idx = t & 63;
    const int ot = idx >> 5, hf = (idx >> 4) & 1, r = idx & 15;
    const int o = ot * 32 + (r & 3) + 8 * (r >> 2) + 4 * hf;
    const int it_ = comb >> 1, jt_ = comb & 1;
    const float* wsl = it_ ? (jt_ ? w22 : w12) : (jt_ ? w12 : w11);
    tblW[comb][idx] = -2.f * wsl[o];
  }
  if (w < 4) {                          // swv per comb, one wave each
    const int it_ = w >> 1, jt_ = w & 1;
    const float* wsl = it_ ? (jt_ ? w22 : w12) : (jt_ ? w12 : w11);
    const float s = wred_sum(wsl[lane]);
    if (lane == 0) swv4[w] = s;
  }

  // W^T fragments in regs (32 VGPR, proven layout)
  BF8 Wp[2][4];
#pragma unroll
  for (int ot = 0; ot < 2; ++ot)
#pragma unroll
    for (int kt = 0; kt < 4; ++kt) {
      const int o = ot * 32 + l31;
#pragma unroll
      for (int p = 0; p < 4; ++p) {
        const int d0 = kt * 16 + half * 8 + 2 * p;
        Wp[ot][kt].u[p] = cvtpk_bf16(W_att[d0 * DD + o], W_att[(d0 + 1) * DD + o]);
      }
    }

  __syncthreads();

  // job list: strip A rows {2bx, 2bx+1}, chunks [bx>>4, 16); strip B rows
  // {510-2bx, 511-2bx}, chunks [(255-bx)>>4, 16). Total 17 chunks -> 34 jobs.
  const int cminA = bx >> 4;
  const int n32A = 16 - cminA;
  const int rB = 510 - 2 * bx;
  const int cminB = (255 - bx) >> 4;
  const int njobs = 2 * (n32A + (16 - cminB));   // = 34

#pragma unroll 1
  for (int t = w; t < njobs; t += 8) {
    int row, c32;
    if (t < 2 * n32A) { row = 2 * bx + (t & 1); c32 = cminA + (t >> 1); }
    else { const int tp = t - 2 * n32A; row = rB + (tp & 1); c32 = cminB + (tp >> 1); }
    const int j0 = c32 * 32;
    const int comb = ((row >= NH) ? 2 : 0) | ((j0 >= NH) ? 1 : 0);

    // load xi (row) and xj (j0+l31) slices, packed bf16 (proven pattern)
    BF8 Xi[4], Xj[4];
#pragma unroll
    for (int kt = 0; kt < 4; ++kt) {
      const float* bi = Xb + row * DD + kt * 16 + half * 8;
      const float4 a = *reinterpret_cast<const float4*>(bi);
      const float4 c = *reinterpret_cast<const float4*>(bi + 4);
      Xi[kt].u[0] = cvtpk_bf16(a.x, a.y);
      Xi[kt].u[1] = cvtpk_bf16(a.z, a.w);
      Xi[kt].u[2] = cvtpk_bf16(c.x, c.y);
      Xi[kt].u[3] = cvtpk_bf16(c.z, c.w);
      const float* bj = Xb + (j0 + l31) * DD + kt * 16 + half * 8;
      const float4 aj = *reinterpret_cast<const float4*>(bj);
      const float4 cj = *reinterpret_cast<const float4*>(bj + 4);
      Xj[kt].u[0] = cvtpk_bf16(aj.x, aj.y);
      Xj[kt].u[1] = cvtpk_bf16(aj.z, aj.w);
      Xj[kt].u[2] = cvtpk_bf16(cj.x, cj.y);
      Xj[kt].u[3] = cvtpk_bf16(cj.z, cj.w);
    }

    f32x16 C0 = {}, C1 = {};
#pragma unroll
    for (int kt = 0; kt < 4; ++kt) {
      BF8 Bi;
#pragma unroll
      for (int p = 0; p < 4; ++p)
        Bi.u[p] = cvtpk_bf16(bflo(Xi[kt].u[p]) * bflo(Xj[kt].u[p]),
                             bfhi(Xi[kt].u[p]) * bfhi(Xj[kt].u[p]));
      C0 = __builtin_amdgcn_mfma_f32_32x32x16_bf16(Wp[0][kt].v, Bi.v, C0, 0, 0, 0);
      C1 = __builtin_amdgcn_mfma_f32_32x32x16_bf16(Wp[1][kt].v, Bi.v, C1, 0, 0, 0);
    }

    // epilogue (proven): arg = K2E*C + tblB; p += tblW * rcp(2^arg + 1)
    float p = 0.f;
    const int base = half * 16;
#pragma unroll
    for (int r = 0; r < 16; ++r) {
      const float a0 = fmaf(C0[r], K2E, tblB[base + r]);
      const float e0 = fast_exp2(a0);
      p = fmaf(tblW[comb][base + r], __builtin_amdgcn_rcpf(e0 + 1.f), p);
      const float a1 = fmaf(C1[r], K2E, tblB[32 + base + r]);
      const float e1 = fast_exp2(a1);
      p = fmaf(tblW[comb][32 + base + r], __builtin_amdgcn_rcpf(e1 + 1.f), p);
    }
    p += __shfl_xor(p, 32);
    if (lane < 32) {
      const int j = j0 + l31;
      if (j >= row) {                     // single-writer ownership
        const float val = swv4[comb] + p;
        scb[row * NN + j] = val;
        if (j > row) scb[j * NN + row] = val;   // symmetric mirror
      }
    }
  }
}

// K_REST: softmax + agg + y(selu) + logits + master (R8 k3b, passed verbatim).
__global__ __launch_bounds__(1024, 4)
void k_rest(const float* __restrict__ X, const float* __restrict__ scG,
            const float* __restrict__ W_attM, const float* __restrict__ b_attM,
            const float* __restrict__ wM,
            const float* __restrict__ W_pa, const float* __restrict__ b_pa,
            const float* __restrict__ W_po, const float* __restrict__ b_po,
            const float* __restrict__ gamma, const float* __restrict__ beta,
            float* __restrict__ master, float* __restrict__ logits,
            float* __restrict__ out) {
  const int b = blockIdx.y;
  const int i0 = blockIdx.x * 8;
  const int tid = threadIdx.x;
  const int lane = tid & 63;
  const int w = tid >> 6;        // 0..15

  __shared__ __align__(16) float Xlds[NN * DD];   // 128 KB
  __shared__ __align__(16) float scL[8 * NN];     // 16 KB
  __shared__ __align__(16) float red2[16][DD];    // 4 KB
  __shared__ __align__(16) float aggL[8][DD];     // 2 KB
  __shared__ __align__(16) float mastL[64];

  const float* __restrict__ Xb = X + b * NN * DD;

  // stage X[b] f32
  {
    const int c4 = (tid & 15) * 4;
    const int rh = tid >> 4;
#pragma unroll
    for (int it = 0; it < 8; ++it) {
      const int r = it * 64 + rh;
      *reinterpret_cast<float4*>(&Xlds[r * DD + c4]) =
          *reinterpret_cast<const float4*>(&Xb[r * DD + c4]);
    }
  }
  // stage scores
  {
    const int r8 = tid >> 7;
    const int c = (tid & 127) * 4;
    *reinterpret_cast<float4*>(&scL[r8 * NN + c]) =
        *reinterpret_cast<const float4*>(&scG[(b * NN + i0 + r8) * NN + c]);
  }
  __syncthreads();   // bar1

  // master mean
  {
    float s = 0.f;
    for (int r = w * 32; r < w * 32 + 32; ++r) s += Xlds[r * DD + lane];
    red2[w][lane] = s;
  }
  __syncthreads();   // bar2
  if (w == 0) {
    float s = 0.f;
#pragma unroll
    for (int k = 0; k < 16; ++k) s += red2[k][lane];
    s *= (1.f / 512.f);
    mastL[lane] = s;
    if (blockIdx.x == 0) master[b * DD + lane] = s;
  }

  // softmax: 2 waves per row
  const int row = w & 7, part = w >> 3;
  const int irow = i0 + row;
  float v[8];
#pragma unroll
  for (int k = 0; k < 8; ++k) v[k] = scL[row * NN + lane + 64 * k];
  __syncthreads();   // bar3b
  float mx = fmaxf(fmaxf(fmaxf(v[0], v[1]), fmaxf(v[2], v[3])),
                   fmaxf(fmaxf(v[4], v[5]), fmaxf(v[6], v[7])));
  mx = wred_max(mx);
  float ssum = 0.f;
#pragma unroll
  for (int k = 0; k < 8; ++k) { v[k] = __expf(v[k] - mx); ssum += v[k]; }
  ssum = wred_sum(ssum);
  const float inv = __builtin_amdgcn_rcpf(ssum);
#pragma unroll
  for (int k = 0; k < 4; ++k) {
    const int kk = part * 4 + k;
    scL[row * NN + lane + 64 * kk] = v[kk] * inv;
  }

  // agg partial over own j-half
  float a0 = 0.f, a1 = 0.f, a2 = 0.f, a3 = 0.f;
  const float* scr = &scL[row * NN + part * 256];
  const int xof = part * 256 * DD;
  for (int jj = 0; jj < 64; ++jj) {
    const float4 at = *reinterpret_cast<const float4*>(&scr[jj * 4]);
    a0 = fmaf(at.x, Xlds[xof + (jj * 4 + 0) * DD + lane], a0);
    a1 = fmaf(at.y, Xlds[xof + (jj * 4 + 1) * DD + lane], a1);
    a2 = fmaf(at.z, Xlds[xof + (jj * 4 + 2) * DD + lane], a2);
    a3 = fmaf(at.w, Xlds[xof + (jj * 4 + 3) * DD + lane], a3);
  }
  red2[w][lane] = (a0 + a1) + (a2 + a3);
  __syncthreads();   // bar4

  if (part == 0) {
    const float aggv = red2[w][lane] + red2[w + 8][lane];
    aggL[row][lane] = aggv;
    float y = b_pa[lane] + b_po[lane];
#pragma unroll 8
    for (int d = 0; d < DD; ++d) {
      y = fmaf(aggL[row][d], W_pa[d * DD + lane], y);
      y = fmaf(Xlds[irow * DD + d], W_po[d * DD + lane], y);
    }
    const float RSQ = 0.9999950000374997f;
    y = y * RSQ * gamma[lane] + beta[lane];
    const float SC_ = 1.0507009873554805f;
    const float AL = 1.6732632423543772f;
    y = (y > 0.f) ? (SC_ * y) : (SC_ * AL * (__expf(y) - 1.f));
    const int off = (irow < NH) ? ((b * NH + irow) * DD + lane)
                                : (BB * NH * DD + (b * NH + (irow - NH)) * DD + lane);
    out[off] = y;
  } else {
    float lg = b_attM[lane];
#pragma unroll 8
    for (int d = 0; d < DD; ++d)
      lg = fmaf(Xlds[irow * DD + d] * mastL[d], W_attM[d * DD + lane], lg);
    const float th = fast_tanh(lg);
    const float s = wred_sum(th * wM[lane]);
    if (lane == 0) logits[b * NN + irow] = s;
  }
}

// K4: softmax_n(logits) -> agg_m -> master_new (tail of out)
__global__ __launch_bounds__(256)
void k4_master_new(const float* __restrict__ X, const float* __restrict__ master,
                   const float* __restrict__ logits,
                   const float* __restrict__ W_paM, const float* __restrict__ b_paM,
                   const float* __restrict__ W_poM, const float* __restrict__ b_poM,
                   float* __restrict__ out) {
  const int b = blockIdx.x;
  const int tid = threadIdx.x;
  const int lane = tid & 63;
  const int q = tid >> 6;
  __shared__ float red[4][DD];
  __shared__ float r4[4];
  __shared__ float aggm_s[DD];
  __shared__ float mrow_s[DD];
  const float* lg = logits + b * NN;
  const float v0 = lg[tid];
  const float v1 = lg[tid + 256];
  float mx = wred_max(fmaxf(v0, v1));
  if (lane == 0) r4[q] = mx;
  __syncthreads();
  mx = fmaxf(fmaxf(r4[0], r4[1]), fmaxf(r4[2], r4[3]));
  float es = __expf(v0 - mx) + __expf(v1 - mx);
  es = wred_sum(es);
  __syncthreads();
  if (lane == 0) r4[q] = es;
  __syncthreads();
  const float S = r4[0] + r4[1] + r4[2] + r4[3];
  const float invS = 1.f / S;

  float acc = 0.f;
  for (int nn = q * 128; nn < q * 128 + 128; ++nn) {
    const float a = __expf(lg[nn] - mx);
    acc = fmaf(a, X[(b * NN + nn) * DD + lane], acc);
  }
  red[q][lane] = acc;
  __syncthreads();
  if (q == 0) {
    aggm_s[lane] =
        (red[0][lane] + red[1][lane] + red[2][lane] + red[3][lane]) * invS;
    mrow_s[lane] = master[b * DD + lane];
  }
  __syncthreads();
  float p = 0.f;
  for (int d = q * 16; d < q * 16 + 16; ++d) {
    p = fmaf(aggm_s[d], W_paM[d * DD + lane], p);
    p = fmaf(mrow_s[d], W_poM[d * DD + lane], p);
  }
  __syncthreads();
  red[q][lane] = p;
  __syncthreads();
  if (q == 0) {
    out[2 * BB * NH * DD + b * DD + lane] =
        red[0][lane] + red[1][lane] + red[2][lane] + red[3][lane] +
        b_paM[lane] + b_poM[lane];
  }
}

extern "C" void kernel_launch(void* const* d_in, const int* in_sizes, int n_in,
                              void* d_out, int out_size, void* d_ws, size_t ws_size,
                              hipStream_t stream) {
  const float* x1    = (const float*)d_in[0];
  const float* x2    = (const float*)d_in[1];
  const float* W_t1  = (const float*)d_in[2];
  const float* b_t1  = (const float*)d_in[3];
  const float* W_t2  = (const float*)d_in[4];
  const float* b_t2  = (const float*)d_in[5];
  const float* W_att = (const float*)d_in[6];
  const float* b_att = (const float*)d_in[7];
  const float* W_attM = (const float*)d_in[8];
  const float* b_attM = (const float*)d_in[9];
  const float* w11   = (const float*)d_in[10];
  const float* w22   = (const float*)d_in[11];
  const float* w12   = (const float*)d_in[12];
  const float* wM    = (const float*)d_in[13];
  const float* W_pa  = (const float*)d_in[14];
  const float* b_pa  = (const float*)d_in[15];
  const float* W_po  = (const float*)d_in[16];
  const float* b_po  = (const float*)d_in[17];
  const float* W_paM = (const float*)d_in[18];
  const float* b_paM = (const float*)d_in[19];
  const float* W_poM = (const float*)d_in[20];
  const float* b_poM = (const float*)d_in[21];
  const float* gamma = (const float*)d_in[22];
  const float* beta  = (const float*)d_in[23];

  float* ws     = (float*)d_ws;
  float* X      = ws;            // 131072 floats
  float* master = ws + 131072;   // 256
  float* logits = ws + 131328;   // 2048
  float* scG    = ws + 133376;   // 1048576 floats (4 MB)
  float* out    = (float*)d_out;

  k1_build_x<<<512, 256, 0, stream>>>(x1, x2, W_t1, b_t1, W_t2, b_t2, X);
  k_sc<<<dim3(128, 4), 512, 0, stream>>>(X, W_att, b_att, w11, w22, w12, scG);
  k_rest<<<dim3(64, 4), 1024, 0, stream>>>(X, scG, W_attM, b_attM, wM,
                                           W_pa, b_pa, W_po, b_po, gamma, beta,
                                           master, logits, out);
  k4_master_new<<<4, 256, 0, stream>>>(X, master, logits, W_paM, b_paM, W_poM, b_poM, out);
}